// Round 10
// baseline (3065.438 us; speedup 1.0000x reference)
//
#include <hip/hip_runtime.h>

// ---------------------------------------------------------------------------
// LSTM encoder: B=64, S=512, E=256, H=512, gates 4H=2048 (i,f,g,o)
// R10: fine-grained producer-consumer recurrence (no monolithic grid barrier).
//  - 64 blocks x 256 thr (4 waves). Block owns units [blk*8,+8) = W rows
//    [blk*32,+32); wave w = batch tile [w*16,+16). W A-frags register/L2;
//    MFMA A=W, B=h^T -> lane-local pointwise (verified R8/R9).
//  - MFMA slice kk consumes h-units [32kk,+32) = producer blocks 4kk..4kk+3.
//    Consume loop: poll 64 contiguous flags (4 lines) -> ballot -> for each
//    ready 4-block group: coherent 16B h-load + 2 MFMAs. Stragglers overlap
//    with compute of ready slices.
//  - Arrive (EVERY iter): vmcnt(0) -> syncthreads -> thread0 flags[blk]=t+1.
//    Consume at iter t needs flags >= t. Chunk-safe (flags carry global t).
//  - Triple-buffered H (t mod 3): skew<=1 step proven => WAR-safe.
//  R9 post-mortem: lockstep barrier = last-arriver + detect + full compute
//  serialized per step (4.48us); R7/R8/R9 all ~4us regardless of mechanics.
// Pipeline: P (prep/pack) -> Q (xg precompute, verified) -> R (rec3).
// Fallback (ws too small): naive all-f32 kernel.
// ---------------------------------------------------------------------------

typedef _Float16 half2_t __attribute__((ext_vector_type(2)));
typedef _Float16 half8 __attribute__((ext_vector_type(8)));
typedef float f32x4 __attribute__((ext_vector_type(4)));
typedef short short4_t __attribute__((ext_vector_type(4)));

__device__ __forceinline__ float dot2h(int w, int h, float c) {
#if __has_builtin(__builtin_amdgcn_fdot2)
  return __builtin_amdgcn_fdot2(__builtin_bit_cast(half2_t, w),
                                __builtin_bit_cast(half2_t, h), c, false);
#else
  half2_t a = __builtin_bit_cast(half2_t, w);
  half2_t b = __builtin_bit_cast(half2_t, h);
  return fmaf((float)a[1], (float)b[1], fmaf((float)a[0], (float)b[0], c));
#endif
}

__device__ __forceinline__ float sigm(float x) { return 1.0f / (1.0f + __expf(-x)); }
__device__ __forceinline__ float tanh_(float x) { return 1.0f - 2.0f / (__expf(2.0f * x) + 1.0f); }

// Coherent 16B load (bypass L1/L2, read at L3 coherence point), imm offset.
template <int OFF>
__device__ __forceinline__ int4 ld_c16o(const void* p) {
  int4 v;
  asm volatile("global_load_dwordx4 %0, %1, off offset:%2 sc0 sc1"
               : "=v"(v) : "v"(p), "i"(OFF) : "memory");
  return v;
}

// ---------------------------------------------------------------------------
// P: Wd[(blk*32 + u*4+g)*512 + k] = W_hh[(g*512 + blk*8+u)*512 + k]  (f16)
//    Wip[(k2*512+j)*8+g*2+kk] = W_ih[(g*512+j)*256+2*k2+kk] (k2<128)
//    bsum[j*4+g] = b_ih + b_hh ; H0 (first of 3 buffers), cstate, flags zeroed.
// ---------------------------------------------------------------------------
__global__ __launch_bounds__(256) void prep_kernel(
    const float* __restrict__ W_hh, const float* __restrict__ W_ih,
    const float* __restrict__ b_ih, const float* __restrict__ b_hh,
    _Float16* __restrict__ Wd, _Float16* __restrict__ Wip,
    float* __restrict__ bsum, _Float16* __restrict__ Hz,  // H0 only
    float* __restrict__ cstate, unsigned* __restrict__ flags) {
  const int S0 = 1048576;            // Wd elements
  const int S1 = S0 + 65536;         // Wip idx (j,k2)
  const int S2 = S1 + 2048;          // bsum
  const int S3 = S2 + 32768;         // H0 halves (H1/H2 written before read)
  const int S4 = S3 + 32768;         // cstate floats
  const int S5 = S4 + 64;            // flags (64 contiguous dwords)
  for (int idx = blockIdx.x * blockDim.x + threadIdx.x; idx < S5;
       idx += gridDim.x * blockDim.x) {
    if (idx < S0) {
      int k = idx & 511, row = (idx >> 9) & 31, blk = idx >> 14;
      int u = row >> 2, g = row & 3;
      Wd[idx] = (_Float16)W_hh[(size_t)(g * 512 + blk * 8 + u) * 512 + k];
    } else if (idx < S1) {
      int e = idx - S0;
      int j = e & 511, k2 = e >> 9;  // k2 in [0,128)
#pragma unroll
      for (int g = 0; g < 4; ++g) {
        Wip[(size_t)(k2 * 512 + j) * 8 + g * 2 + 0] =
            (_Float16)W_ih[(size_t)(g * 512 + j) * 256 + 2 * k2 + 0];
        Wip[(size_t)(k2 * 512 + j) * 8 + g * 2 + 1] =
            (_Float16)W_ih[(size_t)(g * 512 + j) * 256 + 2 * k2 + 1];
      }
    } else if (idx < S2) {
      int e = idx - S1;
      int j = e >> 2, g = e & 3;
      bsum[e] = b_ih[g * 512 + j] + b_hh[g * 512 + j];
    } else if (idx < S3) {
      Hz[idx - S2] = (_Float16)0.0f;
    } else if (idx < S4) {
      cstate[idx - S3] = 0.0f;
    } else {
      flags[idx - S4] = 0u;
    }
  }
}

// ---------------------------------------------------------------------------
// Q: x_gates (verified). 8 tokens/block, 512 thr.
// ---------------------------------------------------------------------------
__global__ __launch_bounds__(512, 1) void xg_kernel(
    const int* __restrict__ seq, const float* __restrict__ emb,
    const _Float16* __restrict__ Wip, const float* __restrict__ bsum,
    _Float16* __restrict__ xg, int t0, int Tc) {
  __shared__ int toks[8];
  __shared__ __align__(16) _Float16 el[128 * 16];  // [k2][tok][2]
  const int tid = threadIdx.x;
  const int tau0 = blockIdx.x * 8;

  if (tid < 8) {
    int tau = tau0 + tid;
    int b = tau / Tc, tl = tau - b * Tc;
    toks[tid] = seq[b * 512 + t0 + tl];
  }
  __syncthreads();
  for (int e = tid; e < 2048; e += 512) {
    int i = e >> 8, k = e & 255;
    el[((k >> 1) * 8 + i) * 2 + (k & 1)] = (_Float16)emb[(size_t)toks[i] * 256 + k];
  }
  __syncthreads();

  const int j = tid;
  float4 bs = *(const float4*)&bsum[j * 4];
  float acc[8][4];
#pragma unroll
  for (int i = 0; i < 8; ++i) {
    acc[i][0] = bs.x; acc[i][1] = bs.y; acc[i][2] = bs.z; acc[i][3] = bs.w;
  }
  const _Float16* wp = Wip + (size_t)j * 8;
#pragma unroll 2
  for (int k2 = 0; k2 < 128; ++k2) {
    int4 w = *(const int4*)(wp + (size_t)k2 * 4096);
    int4 e0 = *(const int4*)(el + k2 * 16);
    int4 e1 = *(const int4*)(el + k2 * 16 + 8);
    acc[0][0] = dot2h(w.x, e0.x, acc[0][0]); acc[0][1] = dot2h(w.y, e0.x, acc[0][1]);
    acc[0][2] = dot2h(w.z, e0.x, acc[0][2]); acc[0][3] = dot2h(w.w, e0.x, acc[0][3]);
    acc[1][0] = dot2h(w.x, e0.y, acc[1][0]); acc[1][1] = dot2h(w.y, e0.y, acc[1][1]);
    acc[1][2] = dot2h(w.z, e0.y, acc[1][2]); acc[1][3] = dot2h(w.w, e0.y, acc[1][3]);
    acc[2][0] = dot2h(w.x, e0.z, acc[2][0]); acc[2][1] = dot2h(w.y, e0.z, acc[2][1]);
    acc[2][2] = dot2h(w.z, e0.z, acc[2][2]); acc[2][3] = dot2h(w.w, e0.z, acc[2][3]);
    acc[3][0] = dot2h(w.x, e0.w, acc[3][0]); acc[3][1] = dot2h(w.y, e0.w, acc[3][1]);
    acc[3][2] = dot2h(w.z, e0.w, acc[3][2]); acc[3][3] = dot2h(w.w, e0.w, acc[3][3]);
    acc[4][0] = dot2h(w.x, e1.x, acc[4][0]); acc[4][1] = dot2h(w.y, e1.x, acc[4][1]);
    acc[4][2] = dot2h(w.z, e1.x, acc[4][2]); acc[4][3] = dot2h(w.w, e1.x, acc[4][3]);
    acc[5][0] = dot2h(w.x, e1.y, acc[5][0]); acc[5][1] = dot2h(w.y, e1.y, acc[5][1]);
    acc[5][2] = dot2h(w.z, e1.y, acc[5][2]); acc[5][3] = dot2h(w.w, e1.y, acc[5][3]);
    acc[6][0] = dot2h(w.x, e1.z, acc[6][0]); acc[6][1] = dot2h(w.y, e1.z, acc[6][1]);
    acc[6][2] = dot2h(w.z, e1.z, acc[6][2]); acc[6][3] = dot2h(w.w, e1.z, acc[6][3]);
    acc[7][0] = dot2h(w.x, e1.w, acc[7][0]); acc[7][1] = dot2h(w.y, e1.w, acc[7][1]);
    acc[7][2] = dot2h(w.z, e1.w, acc[7][2]); acc[7][3] = dot2h(w.w, e1.w, acc[7][3]);
  }
#pragma unroll
  for (int i = 0; i < 8; ++i) {
    short4_t sv;
    sv[0] = __builtin_bit_cast(short, (_Float16)acc[i][0]);
    sv[1] = __builtin_bit_cast(short, (_Float16)acc[i][1]);
    sv[2] = __builtin_bit_cast(short, (_Float16)acc[i][2]);
    sv[3] = __builtin_bit_cast(short, (_Float16)acc[i][3]);
    *(short4_t*)(xg + ((size_t)(tau0 + i) * 512 + j) * 4) = sv;
  }
}

// ---------------------------------------------------------------------------
// R: rec3 (fine-grained). 64 blocks x 256 thr (4 waves), zero LDS data.
// Lane l (lm=l&15, koct=l>>4): batch pb=w*16+lm, units j0=blk*8+koct, j1=j0+4.
// Iter t: read H[t%3], write H[(t+1)%3].
// Consume: poll flags (lane l reads flags[l]) -> ballot -> ready groups:
// slice kk needs flags[4kk..4kk+3] >= t -> h-load bhv[kk] + 2 MFMA.
// Arrive: vmcnt(0) -> syncthreads -> thread0 flags[blk]=t+1 (every iter).
// ---------------------------------------------------------------------------
__global__ __launch_bounds__(256, 1) void rec3_kernel(
    const _Float16* __restrict__ xg, const _Float16* __restrict__ Wd,
    _Float16* __restrict__ H, float* __restrict__ cstate,
    unsigned* __restrict__ flags, float* __restrict__ out, int t0, int Tc) {
  const int blk = blockIdx.x;
  const int tid = threadIdx.x;
  const int l = tid & 63, w = tid >> 6;
  const int lm = l & 15, koct = l >> 4;
  const int pb = w * 16 + lm;          // batch owned
  const int j0 = blk * 8 + koct;       // unit (row-tile 0)
  const int j1 = j0 + 4;               // unit (row-tile 1)

  // W fragments (A-operand layout: row=lm, k=koct*8+j, col-chunk kk*32)
  half8 Af0[16], Af1[16];
  {
    const _Float16* a0 = Wd + ((size_t)blk * 32 + lm) * 512 + koct * 8;
    const _Float16* a1 = a0 + 16 * 512;
#pragma unroll
    for (int kk = 0; kk < 16; ++kk) {
      Af0[kk] = *(const half8*)(a0 + kk * 32);
      Af1[kk] = *(const half8*)(a1 + kk * 32);
    }
  }

  float c0 = cstate[pb * 512 + j0];
  float c1 = cstate[pb * 512 + j1];

  int rc = t0 % 3;  // read-buffer index (t mod 3)

  for (int tl = 0; tl < Tc; ++tl) {
    const int t = t0 + tl;
    const _Float16* Hc = H + (size_t)rc * 32768;
    const int wc = (rc == 2) ? 0 : rc + 1;
    _Float16* Hn = H + (size_t)wc * 32768;

    // xg loads (plain, L2): issue early, drain under consume loop's vmcnt
    short4_t xs0 = *(const short4_t*)(xg + ((size_t)(pb * Tc + tl) * 512 + j0) * 4);
    short4_t xs1 = *(const short4_t*)(xg + ((size_t)(pb * Tc + tl) * 512 + j1) * 4);

    // ---- fine-grained consume: slice kk ready when blocks 4kk..4kk+3 >= t
    const _Float16* hb = Hc + (size_t)pb * 512 + koct * 8;
    int4 bhv[16];
    f32x4 ac0 = {0.f, 0.f, 0.f, 0.f}, ac1 = {0.f, 0.f, 0.f, 0.f};
    const unsigned tgt = (unsigned)t;
    unsigned done = 0;
    while (done != 0xFFFFu) {
      unsigned f;
      asm volatile("global_load_dword %0, %1, off sc0 sc1"
                   : "=v"(f) : "v"(flags + l) : "memory");
      asm volatile("s_waitcnt vmcnt(0)" ::: "memory");
      unsigned long long rdy = __ballot((int)(f >= tgt));
      unsigned newly = 0;
#define TRYLOAD(KK)                                                          \
  if (!((done >> KK) & 1u) && (((rdy >> (4 * KK)) & 0xFull) == 0xFull)) {    \
    bhv[KK] = ld_c16o<KK * 64>(hb);                                          \
    newly |= (1u << KK);                                                     \
  }
      TRYLOAD(0) TRYLOAD(1) TRYLOAD(2) TRYLOAD(3)
      TRYLOAD(4) TRYLOAD(5) TRYLOAD(6) TRYLOAD(7)
      TRYLOAD(8) TRYLOAD(9) TRYLOAD(10) TRYLOAD(11)
      TRYLOAD(12) TRYLOAD(13) TRYLOAD(14) TRYLOAD(15)
#undef TRYLOAD
      if (newly) {
        asm volatile("s_waitcnt vmcnt(0)" ::: "memory");
        __builtin_amdgcn_sched_barrier(0);
#define DOMFMA(KK)                                                           \
  if ((newly >> KK) & 1u) {                                                  \
    half8 B = __builtin_bit_cast(half8, bhv[KK]);                            \
    ac0 = __builtin_amdgcn_mfma_f32_16x16x32_f16(Af0[KK], B, ac0, 0, 0, 0);  \
    ac1 = __builtin_amdgcn_mfma_f32_16x16x32_f16(Af1[KK], B, ac1, 0, 0, 0);  \
  }
        DOMFMA(0) DOMFMA(1) DOMFMA(2) DOMFMA(3)
        DOMFMA(4) DOMFMA(5) DOMFMA(6) DOMFMA(7)
        DOMFMA(8) DOMFMA(9) DOMFMA(10) DOMFMA(11)
        DOMFMA(12) DOMFMA(13) DOMFMA(14) DOMFMA(15)
#undef DOMFMA
        done |= newly;
      } else {
        __builtin_amdgcn_s_sleep(1);
      }
    }

    // ---- lane-local pointwise (acc regs = gates i,f,g,o of (pb, unit))
    float G0 = (float)__builtin_bit_cast(_Float16, (short)xs0[0]) + ac0[0];
    float G1 = (float)__builtin_bit_cast(_Float16, (short)xs0[1]) + ac0[1];
    float G2 = (float)__builtin_bit_cast(_Float16, (short)xs0[2]) + ac0[2];
    float G3 = (float)__builtin_bit_cast(_Float16, (short)xs0[3]) + ac0[3];
    float ig = sigm(G0), fg = sigm(G1), gg = tanh_(G2), og = sigm(G3);
    c0 = fg * c0 + ig * gg;
    float hn0 = og * tanh_(c0);

    G0 = (float)__builtin_bit_cast(_Float16, (short)xs1[0]) + ac1[0];
    G1 = (float)__builtin_bit_cast(_Float16, (short)xs1[1]) + ac1[1];
    G2 = (float)__builtin_bit_cast(_Float16, (short)xs1[2]) + ac1[2];
    G3 = (float)__builtin_bit_cast(_Float16, (short)xs1[3]) + ac1[3];
    float ig1 = sigm(G0), fg1 = sigm(G1), gg1 = tanh_(G2), og1 = sigm(G3);
    c1 = fg1 * c1 + ig1 * gg1;
    float hn1 = og1 * tanh_(c1);

    // ---- packed coherent h stores (pair units across koct^1 lanes)
    unsigned hq0 = (unsigned)__builtin_bit_cast(unsigned short, (_Float16)hn0);
    unsigned hq1 = (unsigned)__builtin_bit_cast(unsigned short, (_Float16)hn1);
    unsigned nq0 = (unsigned)__shfl_xor((int)hq0, 16, 64);
    unsigned nq1 = (unsigned)__shfl_xor((int)hq1, 16, 64);
    if ((koct & 1) == 0) {
      unsigned* bse = (unsigned*)(Hn + (size_t)pb * 512 + blk * 8);
      __hip_atomic_store(bse + (koct >> 1), hq0 | (nq0 << 16),
                         __ATOMIC_RELAXED, __HIP_MEMORY_SCOPE_AGENT);
      __hip_atomic_store(bse + 2 + (koct >> 1), hq1 | (nq1 << 16),
                         __ATOMIC_RELAXED, __HIP_MEMORY_SCOPE_AGENT);
    }
    if (t == 511) {
      out[pb * 512 + j0] = hn0; out[32768 + pb * 512 + j0] = c0;
      out[pb * 512 + j1] = hn1; out[32768 + pb * 512 + j1] = c1;
    }

    // ---- arrive (every iter): stores drained block-wide, then flag
    asm volatile("s_waitcnt vmcnt(0)" ::: "memory");
    __syncthreads();
    if (tid == 0)
      __hip_atomic_store(flags + blk, (unsigned)(t + 1), __ATOMIC_RELAXED,
                         __HIP_MEMORY_SCOPE_AGENT);
    rc = wc;
  }
  cstate[pb * 512 + j0] = c0;
  cstate[pb * 512 + j1] = c1;
}

// ---------------------------------------------------------------------------
// Fallback: all-f32 straight from inputs (only if ws_size is tiny).
// ---------------------------------------------------------------------------
__global__ __launch_bounds__(512, 1) void naive_kernel(
    const int* __restrict__ seq, const float* __restrict__ emb,
    const float* __restrict__ W_ih, const float* __restrict__ W_hh,
    const float* __restrict__ b_ih, const float* __restrict__ b_hh,
    float* __restrict__ out) {
  __shared__ float hl[512];
  const int b = blockIdx.x, j = threadIdx.x;
  hl[j] = 0.f;
  float c = 0.f;
  __syncthreads();
  for (int t = 0; t < 512; ++t) {
    int tok = seq[b * 512 + t];
    float A[4];
#pragma unroll
    for (int g = 0; g < 4; ++g) A[g] = b_ih[g * 512 + j] + b_hh[g * 512 + j];
    for (int k = 0; k < 256; ++k) {
      float e = emb[(size_t)tok * 256 + k];
#pragma unroll
      for (int g = 0; g < 4; ++g) A[g] += e * W_ih[(size_t)(g * 512 + j) * 256 + k];
    }
    for (int k = 0; k < 512; ++k) {
      float h = hl[k];
#pragma unroll
      for (int g = 0; g < 4; ++g) A[g] += h * W_hh[(size_t)(g * 512 + j) * 512 + k];
    }
    __syncthreads();
    float ig = sigm(A[0]), fg = sigm(A[1]), gg = tanh_(A[2]), og = sigm(A[3]);
    c = fg * c + ig * gg;
    float hn = og * tanh_(c);
    hl[j] = hn;
    __syncthreads();
    if (t == 511) {
      out[b * 512 + j] = hn;
      out[32768 + b * 512 + j] = c;
    }
  }
}

// ---------------------------------------------------------------------------
extern "C" void kernel_launch(void* const* d_in, const int* in_sizes, int n_in,
                              void* d_out, int out_size, void* d_ws, size_t ws_size,
                              hipStream_t stream) {
  const int* seq = (const int*)d_in[0];
  const float* emb = (const float*)d_in[1];
  const float* W_ih = (const float*)d_in[2];
  const float* W_hh = (const float*)d_in[3];
  const float* b_ih = (const float*)d_in[4];
  const float* b_hh = (const float*)d_in[5];
  float* out = (float*)d_out;

  // workspace layout
  char* w = (char*)d_ws;
  _Float16* Wd = (_Float16*)(w + 0);            // 2,097,152 B
  _Float16* Wip = (_Float16*)(w + 2097152);     // 1,048,576 B
  float* bsum = (float*)(w + 3145728);          //     8,192 B
  _Float16* H = (_Float16*)(w + 3153920);       //   196,608 B (3 x 64KB)
  float* cstate = (float*)(w + 3350528);        //   131,072 B
  unsigned* flags = (unsigned*)(w + 3481600);   //     4,096 B (64 used)
  _Float16* xgbuf = (_Float16*)(w + 3485696);   // Tc*262,144 B
  const size_t base = 3485696;

  int Tc = 0;
  const int cands[7] = {512, 256, 128, 64, 32, 16, 8};
  for (int ci = 0; ci < 7; ++ci) {
    if (base + (size_t)cands[ci] * 262144 <= ws_size) { Tc = cands[ci]; break; }
  }

  if (Tc == 0) {
    naive_kernel<<<64, 512, 0, stream>>>(seq, emb, W_ih, W_hh, b_ih, b_hh, out);
    return;
  }

  prep_kernel<<<1024, 256, 0, stream>>>(W_hh, W_ih, b_ih, b_hh, Wd, Wip, bsum,
                                        H, cstate, flags);
  for (int t0 = 0; t0 < 512; t0 += Tc) {
    xg_kernel<<<8 * Tc, 512, 0, stream>>>(seq, emb, Wip, bsum, xgbuf, t0, Tc);
    rec3_kernel<<<64, 256, 0, stream>>>(xgbuf, Wd, H, cstate, flags, out,
                                        t0, Tc);
  }
}